// Round 21
// baseline (2444.690 us; speedup 1.0000x reference)
//
#include <hip/hip_runtime.h>

// Fused flash-style softmax(Q V^T) V, B=4, NQ=NK=4096, D=1024, fp32 in/out.
// Round 21: 16-wave megablock. BQ=64, NW=16 (1024 threads), wave owns a
// 64-d slice. Same r17 1-barrier pipeline + fp16 V prepass; spart fp16
// (r20-verified numerics) to fit 2x double-buffer in LDS (139 KB).
// Why: r16/r20 proved time tracks resident work/CU (not barriers/tiles).
// 16 waves/CU = ~50% occupancy (vs 24%) and V staging bytes per FLOP halve
// (one 64KB V tile now feeds 2x the MFMAs). Grid = 256 blocks = 1/CU.
//   region A_i: QK^T(i) -> spart[i&1] || vt16 loads(i-1) || softmax(i-1)
//   barrier_i
//   region B_i: PV(i-1)   (flows into A_{i+1}, no barrier)

#define NB   4
#define NQL  4096
#define NKL  4096
#define DIM  1024
#define BQ   64
#define BK   32
#define NW   16
#define DSL  64
#define NT   (NKL / BK)    // 128
#define LOG2E 1.44269504088896340736f
#define PBW  40            // pbuf row stride in shorts (80 B)

typedef float f32x4 __attribute__((ext_vector_type(4)));
typedef _Float16 f16x8 __attribute__((ext_vector_type(8)));
typedef short s16x8 __attribute__((ext_vector_type(8)));
typedef short s16x4 __attribute__((ext_vector_type(4)));
typedef short s16x2 __attribute__((ext_vector_type(2)));
typedef unsigned int uint_;

union Frag  { f16x8 v; s16x8 s; _Float16 h[8]; };
union Half4 { s16x4 s; _Float16 h[4]; };
union Half2 { s16x2 s; _Float16 h[2]; };

__device__ __forceinline__ void rawbar() {  // LDS visibility only
    asm volatile("s_waitcnt lgkmcnt(0)\n\ts_barrier" ::: "memory");
}

// ---------------- Prepass: V fp32 -> V16 (row-major) + VT16 (transposed) -----
__global__ void prep_v(const float* __restrict__ Vg, short* __restrict__ v16,
                       short* __restrict__ vt16) {
    __shared__ short lds[64][72];
    const int t   = (int)threadIdx.x;
    const int blk = (int)blockIdx.x;
    const int bb    = blk >> 10;
    const int ktile = (blk >> 4) & 63;
    const int dtile = blk & 15;
    const int k0 = ktile * 64, d0 = dtile * 64;
    const int row = t >> 2;
    const int cb  = (t & 3) * 16;

    const float* src = Vg + ((size_t)(bb * NKL + k0 + row) * DIM + d0 + cb);
    short* vdst = v16 + ((size_t)(bb * NKL + k0 + row) * DIM + d0 + cb);
#pragma unroll
    for (int i = 0; i < 4; ++i) {
        f32x4 x = *(const f32x4*)(src + i * 4);
        s16x4 h;
#pragma unroll
        for (int j = 0; j < 4; ++j)
            h[j] = __builtin_bit_cast(short, (_Float16)x[j]);
        *(s16x4*)(vdst + i * 4) = h;
        *(s16x4*)&lds[row][cb + i * 4] = h;
    }
    __syncthreads();
    short* tdst = vt16 + ((size_t)(bb * DIM + d0 + row) * NKL + k0 + cb);
#pragma unroll
    for (int i = 0; i < 4; ++i) {
        s16x4 h;
#pragma unroll
        for (int j = 0; j < 4; ++j)
            h[j] = lds[cb + i * 4 + j][row];
        *(s16x4*)(tdst + i * 4) = h;
    }
}

// ---------------- Main kernel (MODE 1 = fp16 prepass; MODE 0 = fp32 direct) --
template<int MODE>
__global__ __attribute__((amdgpu_flat_work_group_size(1024, 1024),
                          amdgpu_waves_per_eu(1, 4)))
void attn_f16(const float* __restrict__ Qg, const float* __restrict__ Vg,
              float* __restrict__ Og, const short* __restrict__ v16,
              const short* __restrict__ vt16) {
    __shared__ __align__(16) short spart_h[2][NW][BQ][BK];  // 128 KB, fp16 partials
    __shared__ __align__(16) short pbuf[2][BQ * PBW];       // 10 KB
    __shared__ float arun[2][BQ];
    __shared__ float lsum[BQ];

    const int tid = (int)threadIdx.x;
    const int l   = tid & 63;
    const int w   = tid >> 6;          // 0..15
    const int l15 = l & 15;
    const int lg  = l >> 4;

    // XCD-aware swizzle (256 blocks, 8 XCDs, bijective since 256%8==0)
    const int bid  = (int)blockIdx.x;
    const int orig = (bid & 7) * 32 + (bid >> 3);
    const int b  = orig >> 6;          // 64 q-tiles per batch
    const int qt = orig & 63;
    const int q0 = qt * BQ;
    const int dw = w * DSL;            // 64-d slice per wave

    // Q fragments (B-operand): lane holds Q[q0+qb*16+l15][dw+dc*32+lg*8 .. +7]
    f16x8 qf[4][2];
#pragma unroll
    for (int qb = 0; qb < 4; ++qb)
#pragma unroll
        for (int dc = 0; dc < 2; ++dc) {
            const float* qp = Qg + (size_t)(b * NQL + q0 + qb * 16 + l15) * DIM
                            + dw + dc * 32 + lg * 8;
            f32x4 x0 = *(const f32x4*)qp;
            f32x4 x1 = *(const f32x4*)(qp + 4);
            f16x8 a;
#pragma unroll
            for (int j = 0; j < 4; ++j) { a[j] = (_Float16)x0[j]; a[j + 4] = (_Float16)x1[j]; }
            qf[qb][dc] = a;
        }

    f32x4 oacc[4][4];                  // 4 qb x 4 dg (64-d slice)
#pragma unroll
    for (int qb = 0; qb < 4; ++qb)
#pragma unroll
        for (int dg = 0; dg < 4; ++dg)
            oacc[qb][dg] = (f32x4){0.f, 0.f, 0.f, 0.f};

    f32x4 sacc[2][4];                  // 2 kb x 4 qb
    s16x8 hst[2][2];                   // MODE 1 staging (2 ping-pong x 2 dc)
    f32x4 hst32[2][2][2];              // MODE 0 staging

    auto loadstage = [&](int buf, int kt_, int kb) {
        if constexpr (MODE == 1) {
            const short* vp = v16 + ((size_t)(b * NKL + kt_ * BK + kb * 16 + l15) * DIM
                            + dw + lg * 8);
#pragma unroll
            for (int dc = 0; dc < 2; ++dc)
                hst[buf][dc] = *(const s16x8*)(vp + dc * 32);
        } else {
            const float* vp = Vg + (size_t)(b * NKL + kt_ * BK + kb * 16 + l15) * DIM
                            + dw + lg * 8;
#pragma unroll
            for (int dc = 0; dc < 2; ++dc) {
                hst32[buf][dc][0] = *(const f32x4*)(vp + dc * 32);
                hst32[buf][dc][1] = *(const f32x4*)(vp + dc * 32 + 4);
            }
        }
    };

    auto qkt_half = [&](int buf, int kb) {
#pragma unroll
        for (int dc = 0; dc < 2; ++dc) {
            Frag fa;
            if constexpr (MODE == 1) {
                fa.s = hst[buf][dc];
            } else {
#pragma unroll
                for (int j = 0; j < 4; ++j) {
                    fa.h[j]     = (_Float16)hst32[buf][dc][0][j];
                    fa.h[j + 4] = (_Float16)hst32[buf][dc][1][j];
                }
            }
#pragma unroll
            for (int qb = 0; qb < 4; ++qb)
                sacc[kb][qb] = __builtin_amdgcn_mfma_f32_16x16x32_f16(
                    fa.v, qf[qb][dc], sacc[kb][qb], 0, 0, 0);
        }
    };

    auto qkt_tile = [&](int kt_, int spbuf) {
#pragma unroll
        for (int kb = 0; kb < 2; ++kb)
#pragma unroll
            for (int qb = 0; qb < 4; ++qb)
                sacc[kb][qb] = (f32x4){0.f, 0.f, 0.f, 0.f};
        const int ktn = (kt_ + 1 < NT) ? kt_ + 1 : NT - 1;
        qkt_half(0, 0);
        loadstage(0, ktn, 0);
        qkt_half(1, 1);
        loadstage(1, ktn, 1);
        // S^T partials -> spart_h, fp16-packed s16x4 at XOR-swizzled k-group
#pragma unroll
        for (int kb = 0; kb < 2; ++kb)
#pragma unroll
            for (int qb = 0; qb < 4; ++qb) {
                const int q = qb * 16 + l15;
                const int kblk = (kb * 16 + lg * 4) ^ ((q & 7) << 2);
                Half4 pk;
#pragma unroll
                for (int r = 0; r < 4; ++r)
                    pk.h[r] = (_Float16)sacc[kb][qb][r];
                *(s16x4*)&spart_h[spbuf][w][q][kblk] = pk.s;
            }
    };

    // softmax: 64 16-lane groups, group g = 4w+lg handles q = g (unique)
    const int qsm = 4 * w + lg;
    const int kk  = (2 * l15) ^ ((qsm & 7) << 2);

    float m_reg  = -3e38f;
    float l_lane = 0.f;

    auto softmax_tile = [&](int cur) {
        float s0 = 0.f, s1 = 0.f;
#pragma unroll
        for (int wv = 0; wv < NW; ++wv) {
            Half2 hp;
            hp.s = *(const s16x2*)&spart_h[cur][wv][qsm][kk];
            s0 += (float)hp.h[0];
            s1 += (float)hp.h[1];
        }
        float smax = fmaxf(s0, s1);
        float alpha = 1.0f;
        if (!__all(smax - m_reg <= 8.0f)) {
            float mloc = smax;
#pragma unroll
            for (int off = 1; off < 16; off <<= 1)
                mloc = fmaxf(mloc, __shfl_xor(mloc, off));
            float mnew = fmaxf(m_reg, mloc);
            alpha = exp2f((m_reg - mnew) * LOG2E);
            m_reg = mnew;
        }
        float p0 = exp2f((s0 - m_reg) * LOG2E);
        float p1 = exp2f((s1 - m_reg) * LOG2E);
        l_lane = alpha * l_lane + (p0 + p1);
        if (l15 == 0) arun[cur][qsm] = alpha;
        uint_ pk = (uint_)__builtin_bit_cast(unsigned short, (_Float16)p0)
                 | ((uint_)__builtin_bit_cast(unsigned short, (_Float16)p1) << 16);
        *(uint_*)&pbuf[cur][qsm * PBW + 2 * l15] = pk;
    };

    s16x8 pvreg[4];                    // MODE 1: vt16 frags (region A preload)
    float pv32[4][8];                  // MODE 0 fallback

    auto pv_loads = [&](int kt_) {
        if constexpr (MODE == 1) {
            const short* vtb = vt16 + ((size_t)(b * DIM + dw + l15) * NKL
                             + kt_ * BK + lg * 8);
#pragma unroll
            for (int dg = 0; dg < 4; ++dg)
                pvreg[dg] = *(const s16x8*)(vtb + (size_t)dg * 16 * NKL);
        }
    };

    auto pv_tile = [&](int kt_, int cur) {
        if constexpr (MODE == 0) {
            const float* vb = Vg + (size_t)(b * NKL + kt_ * BK + lg * 8) * DIM
                            + dw + l15;
#pragma unroll
            for (int dg = 0; dg < 4; ++dg)
#pragma unroll
                for (int j = 0; j < 8; ++j)
                    pv32[dg][j] = vb[(size_t)j * DIM + dg * 16];
        }
        f32x4 av[4];
#pragma unroll
        for (int qb = 0; qb < 4; ++qb)
            av[qb] = *(const f32x4*)&arun[cur][qb * 16 + lg * 4];
        bool mine1 = true;
#pragma unroll
        for (int qb = 0; qb < 4; ++qb)
#pragma unroll
            for (int r = 0; r < 4; ++r)
                mine1 = mine1 && (av[qb][r] == 1.0f);
        if (!__all(mine1)) {
#pragma unroll
            for (int qb = 0; qb < 4; ++qb)
#pragma unroll
                for (int dg = 0; dg < 4; ++dg)
#pragma unroll
                    for (int r = 0; r < 4; ++r)
                        oacc[qb][dg][r] *= av[qb][r];
        }
        Frag pf[4];
#pragma unroll
        for (int qb = 0; qb < 4; ++qb)
            pf[qb].s = *(const s16x8*)&pbuf[cur][(qb * 16 + l15) * PBW + lg * 8];
#pragma unroll
        for (int dg = 0; dg < 4; ++dg) {
            Frag bf;
            if constexpr (MODE == 1) {
                bf.s = pvreg[dg];
            } else {
#pragma unroll
                for (int j = 0; j < 8; ++j)
                    bf.h[j] = (_Float16)pv32[dg][j];
            }
            __builtin_amdgcn_s_setprio(1);
#pragma unroll
            for (int qb = 0; qb < 4; ++qb)
                oacc[qb][dg] = __builtin_amdgcn_mfma_f32_16x16x32_f16(
                    pf[qb].v, bf.v, oacc[qb][dg], 0, 0, 0);
            __builtin_amdgcn_s_setprio(0);
        }
    };

    // ---- Prologue: stage tile 0, QK^T(0) -> spart[0], barrier
    loadstage(0, 0, 0);
    loadstage(1, 0, 1);
    qkt_tile(0, 0);
    rawbar();

    // ---- Pipelined main loop: one barrier per tile
    for (int kt = 1; kt < NT; ++kt) {
        const int cur = (kt - 1) & 1;
        pv_loads(kt - 1);
        qkt_tile(kt, kt & 1);
        softmax_tile(cur);
        rawbar();
        pv_tile(kt - 1, cur);
    }

    // ---- Tail: softmax + PV for tile NT-1
    {
        const int cur = (NT - 1) & 1;
        pv_loads(NT - 1);
        softmax_tile(cur);
        rawbar();
        pv_tile(NT - 1, cur);
    }

    // ---- Epilogue: reduce l across the 16-lane group, normalize, store
    {
        float rs = l_lane;
#pragma unroll
        for (int off = 1; off < 16; off <<= 1)
            rs += __shfl_xor(rs, off);
        if (l15 == 0) lsum[qsm] = rs;
    }
    __syncthreads();
#pragma unroll
    for (int qb = 0; qb < 4; ++qb) {
        f32x4 lv = *(const f32x4*)&lsum[qb * 16 + lg * 4];
        float il[4];
#pragma unroll
        for (int r = 0; r < 4; ++r) il[r] = 1.0f / lv[r];
#pragma unroll
        for (int dg = 0; dg < 4; ++dg)
#pragma unroll
            for (int r = 0; r < 4; ++r) {
                int q = q0 + qb * 16 + lg * 4 + r;
                int d = dw + dg * 16 + l15;
                Og[(size_t)(b * NQL + q) * DIM + d] = oacc[qb][dg][r] * il[r];
            }
    }
}

extern "C" void kernel_launch(void* const* d_in, const int* in_sizes, int n_in,
                              void* d_out, int out_size, void* d_ws, size_t ws_size,
                              hipStream_t stream) {
    const float* Q = (const float*)d_in[0];
    const float* V = (const float*)d_in[1];
    float* O = (float*)d_out;
    (void)in_sizes; (void)n_in; (void)out_size;

    const size_t elems = (size_t)NB * NKL * DIM;          // 16.78M
    const size_t need  = 2 * elems * sizeof(short);       // 64 MB
    dim3 grid(NB * (NQL / BQ));  // 256 blocks (1 per CU)
    dim3 block(NW * 64);         // 1024 threads
    if (ws_size >= need) {
        short* v16  = (short*)d_ws;
        short* vt16 = v16 + elems;
        prep_v<<<dim3(NB * 1024), dim3(256), 0, stream>>>(V, v16, vt16);
        attn_f16<1><<<grid, block, 0, stream>>>(Q, V, O, v16, vt16);
    } else {
        attn_f16<0><<<grid, block, 0, stream>>>(Q, V, O, nullptr, nullptr);
    }
}

// Round 22
// 934.243 us; speedup vs baseline: 2.6168x; 2.6168x over previous
//
#include <hip/hip_runtime.h>

// Fused flash-style softmax(Q V^T) V, B=4, NQ=NK=4096, D=1024, fp32 in/out.
// Round 22: restore round-20 (best, 934 us) and remove the s_setprio toggles
// around the PV MFMAs (m190: setprio is null-to-negative for barrier-lockstep
// blocks; 32 SALU toggle pairs/tile of pure overhead).
// Structure (1 barrier per 64-k tile, BK=64):
//   region A_i: QK^T(i,4 halves) -> spart_h[i&1] || vt16 chunk0(i-1) || softmax(i-1)
//   barrier_i
//   region B_i: PV(i-1) chunks 0,1   (flows into A_{i+1}, no barrier)
// fp16 V prepass in d_ws: V16 (QK^T staging, no cvt) + VT16 (PV frags, no cvt).

#define NB   4
#define NQL  4096
#define NKL  4096
#define DIM  1024
#define BQ   32
#define BK   64
#define NW   8
#define DSL  128
#define NT   (NKL / BK)    // 64
#define LOG2E 1.44269504088896340736f
#define PBW  72            // pbuf row stride in shorts (144 B, 16B-aligned)

typedef float f32x4 __attribute__((ext_vector_type(4)));
typedef _Float16 f16x8 __attribute__((ext_vector_type(8)));
typedef short s16x8 __attribute__((ext_vector_type(8)));
typedef short s16x4 __attribute__((ext_vector_type(4)));

union Frag  { f16x8 v; s16x8 s; _Float16 h[8]; };
union Half4 { s16x4 s; _Float16 h[4]; };

__device__ __forceinline__ void rawbar() {  // LDS visibility only
    asm volatile("s_waitcnt lgkmcnt(0)\n\ts_barrier" ::: "memory");
}

// ---------------- Prepass: V fp32 -> V16 (row-major) + VT16 (transposed) -----
__global__ void prep_v(const float* __restrict__ Vg, short* __restrict__ v16,
                       short* __restrict__ vt16) {
    __shared__ short lds[64][72];
    const int t   = (int)threadIdx.x;
    const int blk = (int)blockIdx.x;
    const int bb    = blk >> 10;
    const int ktile = (blk >> 4) & 63;
    const int dtile = blk & 15;
    const int k0 = ktile * 64, d0 = dtile * 64;
    const int row = t >> 2;
    const int cb  = (t & 3) * 16;

    const float* src = Vg + ((size_t)(bb * NKL + k0 + row) * DIM + d0 + cb);
    short* vdst = v16 + ((size_t)(bb * NKL + k0 + row) * DIM + d0 + cb);
#pragma unroll
    for (int i = 0; i < 4; ++i) {
        f32x4 x = *(const f32x4*)(src + i * 4);
        s16x4 h;
#pragma unroll
        for (int j = 0; j < 4; ++j)
            h[j] = __builtin_bit_cast(short, (_Float16)x[j]);
        *(s16x4*)(vdst + i * 4) = h;
        *(s16x4*)&lds[row][cb + i * 4] = h;
    }
    __syncthreads();
    short* tdst = vt16 + ((size_t)(bb * DIM + d0 + row) * NKL + k0 + cb);
#pragma unroll
    for (int i = 0; i < 4; ++i) {
        s16x4 h;
#pragma unroll
        for (int j = 0; j < 4; ++j)
            h[j] = lds[cb + i * 4 + j][row];
        *(s16x4*)(tdst + i * 4) = h;
    }
}

// ---------------- Main kernel (MODE 1 = fp16 prepass; MODE 0 = fp32 direct) --
template<int MODE>
__global__ __attribute__((amdgpu_flat_work_group_size(512, 512),
                          amdgpu_waves_per_eu(1, 4)))
void attn_f16(const float* __restrict__ Qg, const float* __restrict__ Vg,
              float* __restrict__ Og, const short* __restrict__ v16,
              const short* __restrict__ vt16) {
    __shared__ __align__(16) short spart_h[2][NW][BQ][BK];  // 64 KB, fp16 partials
    __shared__ __align__(16) short pbuf[2][BQ * PBW];       // 9216 B
    __shared__ float arun[2][BQ];
    __shared__ float lsum[BQ];

    const int tid = (int)threadIdx.x;
    const int l   = tid & 63;
    const int w   = tid >> 6;
    const int l15 = l & 15;
    const int lg  = l >> 4;

    // XCD-aware swizzle (512 blocks, 8 XCDs, bijective)
    const int bid  = (int)blockIdx.x;
    const int orig = (bid & 7) * 64 + (bid >> 3);
    const int b  = orig >> 7;
    const int qt = orig & 127;
    const int q0 = qt * BQ;
    const int dw = w * DSL;

    // Q fragments (B-operand), fp32->fp16 once per block
    f16x8 qf[2][4];
#pragma unroll
    for (int qb = 0; qb < 2; ++qb)
#pragma unroll
        for (int dc = 0; dc < 4; ++dc) {
            const float* qp = Qg + (size_t)(b * NQL + q0 + qb * 16 + l15) * DIM
                            + dw + dc * 32 + lg * 8;
            f32x4 x0 = *(const f32x4*)qp;
            f32x4 x1 = *(const f32x4*)(qp + 4);
            f16x8 a;
#pragma unroll
            for (int j = 0; j < 4; ++j) { a[j] = (_Float16)x0[j]; a[j + 4] = (_Float16)x1[j]; }
            qf[qb][dc] = a;
        }

    f32x4 oacc[2][8];
#pragma unroll
    for (int qb = 0; qb < 2; ++qb)
#pragma unroll
        for (int dg = 0; dg < 8; ++dg)
            oacc[qb][dg] = (f32x4){0.f, 0.f, 0.f, 0.f};

    f32x4 sacc[4][2];               // 4 k-halves x 2 q-blocks
    s16x8 hst[2][4];                // MODE 1 staging, 2 ping-pong buffers
    f32x4 hst32[2][4][2];           // MODE 0 staging

    auto loadstage = [&](int buf, int kt_, int kb) {
        if constexpr (MODE == 1) {
            const short* vp = v16 + ((size_t)(b * NKL + kt_ * BK + kb * 16 + l15) * DIM
                            + dw + lg * 8);
#pragma unroll
            for (int dc = 0; dc < 4; ++dc)
                hst[buf][dc] = *(const s16x8*)(vp + dc * 32);
        } else {
            const float* vp = Vg + (size_t)(b * NKL + kt_ * BK + kb * 16 + l15) * DIM
                            + dw + lg * 8;
#pragma unroll
            for (int dc = 0; dc < 4; ++dc) {
                hst32[buf][dc][0] = *(const f32x4*)(vp + dc * 32);
                hst32[buf][dc][1] = *(const f32x4*)(vp + dc * 32 + 4);
            }
        }
    };

    auto qkt_half = [&](int buf, int kb) {
#pragma unroll
        for (int dc = 0; dc < 4; ++dc) {
            Frag fa;
            if constexpr (MODE == 1) {
                fa.s = hst[buf][dc];
            } else {
#pragma unroll
                for (int j = 0; j < 4; ++j) {
                    fa.h[j]     = (_Float16)hst32[buf][dc][0][j];
                    fa.h[j + 4] = (_Float16)hst32[buf][dc][1][j];
                }
            }
            sacc[kb][0] = __builtin_amdgcn_mfma_f32_16x16x32_f16(fa.v, qf[0][dc], sacc[kb][0], 0, 0, 0);
            sacc[kb][1] = __builtin_amdgcn_mfma_f32_16x16x32_f16(fa.v, qf[1][dc], sacc[kb][1], 0, 0, 0);
        }
    };

    auto qkt_tile = [&](int kt_, int spbuf) {
#pragma unroll
        for (int kb = 0; kb < 4; ++kb)
#pragma unroll
            for (int qb = 0; qb < 2; ++qb)
                sacc[kb][qb] = (f32x4){0.f, 0.f, 0.f, 0.f};
        const int ktn = (kt_ + 1 < NT) ? kt_ + 1 : NT - 1;
        // 4 k-halves through 2 staging buffers; final 2 loads prefetch tile ktn
        qkt_half(0, 0);  loadstage(0, kt_, 2);
        qkt_half(1, 1);  loadstage(1, kt_, 3);
        qkt_half(0, 2);  loadstage(0, ktn, 0);
        qkt_half(1, 3);  loadstage(1, ktn, 1);
        // S^T partials -> spart_h, fp16-packed s16x4 at XOR-swizzled k-group
#pragma unroll
        for (int kb = 0; kb < 4; ++kb)
#pragma unroll
            for (int qb = 0; qb < 2; ++qb) {
                const int q = qb * 16 + l15;
                const int kblk = (kb * 16 + lg * 4) ^ ((q & 7) << 2);
                Half4 pk;
#pragma unroll
                for (int r = 0; r < 4; ++r)
                    pk.h[r] = (_Float16)sacc[kb][qb][r];
                *(s16x4*)&spart_h[spbuf][w][q][kblk] = pk.s;
            }
    };

    // softmax: lane group handles q = 4w+lg, adjacent k-quad {4*l15 .. +3}
    const int qsm = 4 * w + lg;
    const int kk  = (4 * l15) ^ ((qsm & 7) << 2);

    float m_reg  = -3e38f;
    float l_lane = 0.f;

    auto softmax_tile = [&](int cur) {
        float s[4] = {0.f, 0.f, 0.f, 0.f};
#pragma unroll
        for (int wv = 0; wv < NW; ++wv) {
            Half4 hp;
            hp.s = *(const s16x4*)&spart_h[cur][wv][qsm][kk];
#pragma unroll
            for (int r = 0; r < 4; ++r)
                s[r] += (float)hp.h[r];
        }
        float smax = fmaxf(fmaxf(s[0], s[1]), fmaxf(s[2], s[3]));
        float alpha = 1.0f;
        if (!__all(smax - m_reg <= 8.0f)) {
            float mloc = smax;
#pragma unroll
            for (int off = 1; off < 16; off <<= 1)
                mloc = fmaxf(mloc, __shfl_xor(mloc, off));
            float mnew = fmaxf(m_reg, mloc);
            alpha = exp2f((m_reg - mnew) * LOG2E);
            m_reg = mnew;
        }
        float psum = 0.f;
        Half4 pk;
#pragma unroll
        for (int r = 0; r < 4; ++r) {
            float p = exp2f((s[r] - m_reg) * LOG2E);
            psum += p;
            pk.h[r] = (_Float16)p;
        }
        l_lane = alpha * l_lane + psum;
        if (l15 == 0) arun[cur][qsm] = alpha;
        *(s16x4*)&pbuf[cur][qsm * PBW + 4 * l15] = pk.s;
    };

    s16x8 pvreg[8];                 // MODE 1: chunk-0 vt16 frags (region A)

    auto pv_loads = [&](int kt_) {
        if constexpr (MODE == 1) {
            const short* vtb = vt16 + ((size_t)(b * DIM + dw + l15) * NKL
                             + kt_ * BK + lg * 8);
#pragma unroll
            for (int dg = 0; dg < 8; ++dg)
                pvreg[dg] = *(const s16x8*)(vtb + (size_t)dg * 16 * NKL);
        }
    };

    auto pv_tile = [&](int kt_, int cur) {
        // chunk-1 loads first: latency hides under rescale + chunk-0 MFMAs
        s16x8 pv1[8];
        if constexpr (MODE == 1) {
            const short* vtb = vt16 + ((size_t)(b * DIM + dw + l15) * NKL
                             + kt_ * BK + lg * 8);
#pragma unroll
            for (int dg = 0; dg < 8; ++dg)
                pv1[dg] = *(const s16x8*)(vtb + (size_t)dg * 16 * NKL + 32);
        }
        f32x4 av[2];
#pragma unroll
        for (int qb = 0; qb < 2; ++qb)
            av[qb] = *(const f32x4*)&arun[cur][qb * 16 + lg * 4];
        bool mine1 = true;
#pragma unroll
        for (int qb = 0; qb < 2; ++qb)
#pragma unroll
            for (int r = 0; r < 4; ++r)
                mine1 = mine1 && (av[qb][r] == 1.0f);
        if (!__all(mine1)) {
#pragma unroll
            for (int qb = 0; qb < 2; ++qb)
#pragma unroll
                for (int dg = 0; dg < 8; ++dg)
#pragma unroll
                    for (int r = 0; r < 4; ++r)
                        oacc[qb][dg][r] *= av[qb][r];
        }
        Frag pf[2][2];
#pragma unroll
        for (int qb = 0; qb < 2; ++qb)
#pragma unroll
            for (int c = 0; c < 2; ++c)
                pf[qb][c].s = *(const s16x8*)&pbuf[cur][(qb * 16 + l15) * PBW
                                                        + c * 32 + lg * 8];
        if constexpr (MODE == 1) {
#pragma unroll
            for (int dg = 0; dg < 8; ++dg)
#pragma unroll
                for (int qb = 0; qb < 2; ++qb)
                    oacc[qb][dg] = __builtin_amdgcn_mfma_f32_16x16x32_f16(
                        pf[qb][0].v, (Frag{.s = pvreg[dg]}).v, oacc[qb][dg], 0, 0, 0);
#pragma unroll
            for (int dg = 0; dg < 8; ++dg)
#pragma unroll
                for (int qb = 0; qb < 2; ++qb)
                    oacc[qb][dg] = __builtin_amdgcn_mfma_f32_16x16x32_f16(
                        pf[qb][1].v, (Frag{.s = pv1[dg]}).v, oacc[qb][dg], 0, 0, 0);
        } else {
            // fp32 gather fallback, chunk by chunk
#pragma unroll
            for (int c = 0; c < 2; ++c) {
                const float* vb = Vg + (size_t)(b * NKL + kt_ * BK + c * 32 + lg * 8) * DIM
                                + dw + l15;
#pragma unroll
                for (int dg = 0; dg < 8; ++dg) {
                    Frag bf;
#pragma unroll
                    for (int j = 0; j < 8; ++j)
                        bf.h[j] = (_Float16)vb[(size_t)j * DIM + dg * 16];
#pragma unroll
                    for (int qb = 0; qb < 2; ++qb)
                        oacc[qb][dg] = __builtin_amdgcn_mfma_f32_16x16x32_f16(
                            pf[qb][c].v, bf.v, oacc[qb][dg], 0, 0, 0);
                }
            }
        }
    };

    // ---- Prologue: stage tile 0 (kb0,kb1), QK^T(0) -> spart_h[0], barrier
    loadstage(0, 0, 0);
    loadstage(1, 0, 1);
    qkt_tile(0, 0);
    rawbar();

    // ---- Pipelined main loop: one barrier per 64-k tile
    for (int kt = 1; kt < NT; ++kt) {
        const int cur = (kt - 1) & 1;
        pv_loads(kt - 1);
        qkt_tile(kt, kt & 1);
        softmax_tile(cur);
        rawbar();
        pv_tile(kt - 1, cur);
    }

    // ---- Tail: softmax + PV for tile NT-1
    {
        const int cur = (NT - 1) & 1;
        pv_loads(NT - 1);
        softmax_tile(cur);
        rawbar();
        pv_tile(NT - 1, cur);
    }

    // ---- Epilogue: reduce l across the 16-lane group, normalize, store
    {
        float rs = l_lane;
#pragma unroll
        for (int off = 1; off < 16; off <<= 1)
            rs += __shfl_xor(rs, off);
        if (l15 == 0) lsum[qsm] = rs;
    }
    __syncthreads();
#pragma unroll
    for (int qb = 0; qb < 2; ++qb) {
        f32x4 lv = *(const f32x4*)&lsum[qb * 16 + lg * 4];
        float il[4];
#pragma unroll
        for (int r = 0; r < 4; ++r) il[r] = 1.0f / lv[r];
#pragma unroll
        for (int dg = 0; dg < 8; ++dg)
#pragma unroll
            for (int r = 0; r < 4; ++r) {
                int q = q0 + qb * 16 + lg * 4 + r;
                int d = dw + dg * 16 + l15;
                Og[(size_t)(b * NQL + q) * DIM + d] = oacc[qb][dg][r] * il[r];
            }
    }
}

extern "C" void kernel_launch(void* const* d_in, const int* in_sizes, int n_in,
                              void* d_out, int out_size, void* d_ws, size_t ws_size,
                              hipStream_t stream) {
    const float* Q = (const float*)d_in[0];
    const float* V = (const float*)d_in[1];
    float* O = (float*)d_out;
    (void)in_sizes; (void)n_in; (void)out_size;

    const size_t elems = (size_t)NB * NKL * DIM;          // 16.78M
    const size_t need  = 2 * elems * sizeof(short);       // 64 MB
    dim3 grid(NB * (NQL / BQ));  // 512 blocks
    dim3 block(NW * 64);         // 512 threads
    if (ws_size >= need) {
        short* v16  = (short*)d_ws;
        short* vt16 = v16 + elems;
        prep_v<<<dim3(NB * 1024), dim3(256), 0, stream>>>(V, v16, vt16);
        attn_f16<1><<<grid, block, 0, stream>>>(Q, V, O, v16, vt16);
    } else {
        attn_f16<0><<<grid, block, 0, stream>>>(Q, V, O, nullptr, nullptr);
    }
}